// Round 1
// baseline (4773.414 us; speedup 1.0000x reference)
//
#include <hip/hip_runtime.h>

#define DD 128

typedef __attribute__((ext_vector_type(8))) short short8;
typedef __attribute__((ext_vector_type(4))) float f32x4;

__device__ inline short f2bf(float f) {
    unsigned u = __float_as_uint(f);
    unsigned r = (u + 0x7fffu + ((u >> 16) & 1u)) >> 16;
    return (short)(r & 0xffffu);
}

// ---------------- weight pack: fragment-order bf16 B for mfma_f32_16x16x32_bf16 ----------------
// Bpack[((t*ktiles + kk)*64 + lane)*8 + j] = Wcat[n][k], n = t*16 + (lane&15), k = kk*32 + (lane>>4)*8 + j
// Wcat = [W1 | W2] along k (W2 used for k>=128).
__global__ void pack_w(const float* __restrict__ W1, const float* __restrict__ W2,
                       short* __restrict__ dst, int ktiles) {
    int idx = blockIdx.x * blockDim.x + threadIdx.x;
    int total = 8 * ktiles * 64;
    if (idx >= total) return;
    int lane = idx & 63;
    int kk = (idx >> 6) % ktiles;
    int t = (idx >> 6) / ktiles;
    int n = t * 16 + (lane & 15);
    int kbase = kk * 32 + (lane >> 4) * 8;
    short8 v;
#pragma unroll
    for (int j = 0; j < 8; ++j) {
        int k = kbase + j;
        float f = (k < 128) ? W1[n * 128 + k] : W2[n * 128 + (k - 128)];
        v[j] = f2bf(f);
    }
    *(short8*)(dst + (size_t)idx * 8) = v;
}

// ---------------- edge scatter (both directions) ----------------
__global__ __launch_bounds__(256) void scatter_main(
    const float* __restrict__ xa, const float* __restrict__ xp,
    const int* __restrict__ aidx, const int* __restrict__ pidx,
    float* __restrict__ aggA, float* __restrict__ aggP,
    float* __restrict__ degP, float* __restrict__ degA, int E) {
    int g = blockIdx.x * blockDim.x + threadIdx.x;
    int e = g >> 5;
    int l = g & 31;
    if (e >= E) return;
    int a = aidx[e], p = pidx[e];
    float4 va = *(const float4*)(xa + (size_t)a * DD + l * 4);
    float* dA = aggA + (size_t)p * DD + l * 4;
    unsafeAtomicAdd(dA + 0, va.x); unsafeAtomicAdd(dA + 1, va.y);
    unsafeAtomicAdd(dA + 2, va.z); unsafeAtomicAdd(dA + 3, va.w);
    float4 vp = *(const float4*)(xp + (size_t)p * DD + l * 4);
    float* dP = aggP + (size_t)a * DD + l * 4;
    unsafeAtomicAdd(dP + 0, vp.x); unsafeAtomicAdd(dP + 1, vp.y);
    unsafeAtomicAdd(dP + 2, vp.z); unsafeAtomicAdd(dP + 3, vp.w);
    if (l == 0) { unsafeAtomicAdd(degP + p, 1.f); unsafeAtomicAdd(degA + a, 1.f); }
}

__global__ __launch_bounds__(256) void scatter_co(
    const float* __restrict__ xa, const int* __restrict__ src, const int* __restrict__ dst,
    float* __restrict__ aggC, float* __restrict__ degC, int E) {
    int g = blockIdx.x * blockDim.x + threadIdx.x;
    int e = g >> 5;
    int l = g & 31;
    if (e >= E) return;
    int s = src[e], d = dst[e];
    float4 v = *(const float4*)(xa + (size_t)s * DD + l * 4);
    float* dC = aggC + (size_t)d * DD + l * 4;
    unsafeAtomicAdd(dC + 0, v.x); unsafeAtomicAdd(dC + 1, v.y);
    unsafeAtomicAdd(dC + 2, v.z); unsafeAtomicAdd(dC + 3, v.w);
    if (l == 0) unsafeAtomicAdd(degC + d, 1.f);
}

// ---------------- fused node transform: out = A1@W1.T (+ A2@W2.T) + deg*b1 (+ b2) (+ base) ----------------
// KTILES=8: K=256, A = [A1 | A2].  KTILES=4: K=128, A = A1 only.
template <int KTILES, bool HAS_B2, bool ADD_BASE>
__global__ __launch_bounds__(256) void transform_kernel(
    const float* __restrict__ A1, const float* __restrict__ A2,
    const float* __restrict__ base, const short* __restrict__ Bpack,
    const float* __restrict__ deg, const float* __restrict__ b1,
    const float* __restrict__ b2, float* __restrict__ out, int M) {
    const int wave = threadIdx.x >> 6;
    const int lane = threadIdx.x & 63;
    const int kg = lane >> 4;
    const int rowBase = blockIdx.x * 64 + wave * 16;
    const int arow = rowBase + (lane & 15);
    const int arow_c = arow < M ? arow : (M - 1);

    f32x4 acc[8];
#pragma unroll
    for (int t = 0; t < 8; ++t) acc[t] = (f32x4){0.f, 0.f, 0.f, 0.f};

#pragma unroll
    for (int kk = 0; kk < KTILES; ++kk) {
        int k = kk * 32 + kg * 8;
        const float* src;
        if (KTILES == 8 && kk >= 4) src = A2 + (size_t)arow_c * DD + (k - 128);
        else                        src = A1 + (size_t)arow_c * DD + k;
        float4 u0 = *(const float4*)(src);
        float4 u1 = *(const float4*)(src + 4);
        short8 af;
        af[0] = f2bf(u0.x); af[1] = f2bf(u0.y); af[2] = f2bf(u0.z); af[3] = f2bf(u0.w);
        af[4] = f2bf(u1.x); af[5] = f2bf(u1.y); af[6] = f2bf(u1.z); af[7] = f2bf(u1.w);
#pragma unroll
        for (int t = 0; t < 8; ++t) {
            short8 bf = *(const short8*)(Bpack + ((size_t)(t * KTILES + kk) * 64 + lane) * 8);
            acc[t] = __builtin_amdgcn_mfma_f32_16x16x32_bf16(af, bf, acc[t], 0, 0, 0);
        }
    }

    const int col0 = lane & 15;
    const int crow0 = rowBase + kg * 4;
#pragma unroll
    for (int t = 0; t < 8; ++t) {
        int col = t * 16 + col0;
        float bb = b1[col];
        float b2v = HAS_B2 ? b2[col] : 0.f;
#pragma unroll
        for (int r = 0; r < 4; ++r) {
            int row = crow0 + r;
            if (row < M) {
                float v = acc[t][r] + deg[row] * bb + b2v;
                if (ADD_BASE) v += base[(size_t)row * DD + col];
                out[(size_t)row * DD + col] = v;
            }
        }
    }
}

// ---------------- supervision dot ----------------
__global__ __launch_bounds__(256) void dot_kernel(
    const float* __restrict__ xa, const float* __restrict__ xp,
    const int* __restrict__ s0, const int* __restrict__ s1,
    float* __restrict__ out, int E) {
    int g = blockIdx.x * blockDim.x + threadIdx.x;
    int e = g >> 5;
    int l = g & 31;
    if (e >= E) return;
    int a = s0[e], p = s1[e];
    float4 va = *(const float4*)(xa + (size_t)a * DD + l * 4);
    float4 vp = *(const float4*)(xp + (size_t)p * DD + l * 4);
    float s = va.x * vp.x + va.y * vp.y + va.z * vp.z + va.w * vp.w;
    s += __shfl_xor(s, 1); s += __shfl_xor(s, 2); s += __shfl_xor(s, 4);
    s += __shfl_xor(s, 8); s += __shfl_xor(s, 16);
    if (l == 0) out[e] = s;
}

extern "C" void kernel_launch(void* const* d_in, const int* in_sizes, int n_in,
                              void* d_out, int out_size, void* d_ws, size_t ws_size,
                              hipStream_t stream) {
    const float* xa_in = (const float*)d_in[0];
    const float* xp_in = (const float*)d_in[1];
    const int* eidx = (const int*)d_in[2];
    const int* co = (const int*)d_in[3];
    const int* sup = (const int*)d_in[4];
    const float* W_a2p = (const float*)d_in[5];
    const float* b_a2p = (const float*)d_in[6];
    const float* W_p2a = (const float*)d_in[7];
    const float* b_p2a = (const float*)d_in[8];
    const float* W_aself = (const float*)d_in[9];
    const float* b_aself = (const float*)d_in[10];
    const float* W_pself = (const float*)d_in[11];
    const float* b_pself = (const float*)d_in[12];
    const float* W_co = (const float*)d_in[13];
    const float* b_co = (const float*)d_in[14];

    const int NA = in_sizes[0] / DD;
    const int NP = in_sizes[1] / DD;
    const int E = in_sizes[2] / 2;
    const int Eco = in_sizes[3] / 2;
    const int Esup = in_sizes[4] / 2;
    const int* a_idx = eidx;
    const int* p_idx = eidx + E;
    const int* co_s = co;
    const int* co_d = co + Eco;
    const int* s0 = sup;
    const int* s1 = sup + Esup;

    char* w = (char*)d_ws;
    auto carve = [&](size_t bytes) -> char* {
        char* p = w;
        w += (bytes + 255) & ~(size_t)255;
        return p;
    };
    float* P0 = (float*)carve((size_t)NP * DD * 4);   // paper l1 out / aggA l1 / aggC l2
    float* P1 = (float*)carve((size_t)NP * DD * 4);   // aggC l1 / aggA l2 / paper l2 out
    float* A0 = (float*)carve((size_t)NA * DD * 4);   // aggP l1 / author l1 out
    float* A1b = (float*)carve((size_t)NA * DD * 4);  // aggP l2 / author l2 out
    float* degP = (float*)carve((size_t)NP * 4);
    float* degA = (float*)carve((size_t)NA * 4);
    float* degC = (float*)carve((size_t)NA * 4);
    short* BPp0 = (short*)carve(8 * 8 * 64 * 8 * 2);
    short* BPp1 = (short*)carve(8 * 8 * 64 * 8 * 2);
    short* BPa0 = (short*)carve(8 * 8 * 64 * 8 * 2);
    short* BPa1 = (short*)carve(8 * 8 * 64 * 8 * 2);
    short* BPc0 = (short*)carve(8 * 4 * 64 * 8 * 2);
    short* BPc1 = (short*)carve(8 * 4 * 64 * 8 * 2);

    const int WL = 128 * 128;  // per-layer weight stride
    // pack weights (fragment order, bf16)
    pack_w<<<16, 256, 0, stream>>>(W_a2p, W_pself, BPp0, 8);
    pack_w<<<16, 256, 0, stream>>>(W_a2p + WL, W_pself + WL, BPp1, 8);
    pack_w<<<16, 256, 0, stream>>>(W_p2a, W_aself, BPa0, 8);
    pack_w<<<16, 256, 0, stream>>>(W_p2a + WL, W_aself + WL, BPa1, 8);
    pack_w<<<8, 256, 0, stream>>>(W_co, nullptr, BPc0, 4);
    pack_w<<<8, 256, 0, stream>>>(W_co + WL, nullptr, BPc1, 4);

    const int blkP = (NP + 63) / 64;
    const int blkA = (NA + 63) / 64;
    const int sgrid = (E * 32 + 255) / 256;
    const int cgrid = (Eco * 32 + 255) / 256;

    // ---- Layer 1 ----
    hipMemsetAsync(P0, 0, (size_t)NP * DD * 4, stream);
    hipMemsetAsync(A0, 0, (size_t)NA * DD * 4, stream);
    hipMemsetAsync(degP, 0, (size_t)NP * 4, stream);
    hipMemsetAsync(degA, 0, (size_t)NA * 4, stream);
    scatter_main<<<sgrid, 256, 0, stream>>>(xa_in, xp_in, a_idx, p_idx, P0, A0, degP, degA, E);
    transform_kernel<8, true, false><<<blkP, 256, 0, stream>>>(P0, xp_in, nullptr, BPp0, degP, b_a2p, b_pself, P0, NP);
    transform_kernel<8, true, false><<<blkA, 256, 0, stream>>>(A0, xa_in, nullptr, BPa0, degA, b_p2a, b_aself, A0, NA);
    hipMemsetAsync(P1, 0, (size_t)NA * DD * 4, stream);  // aggC (author-sized) in P1 space
    hipMemsetAsync(degC, 0, (size_t)NA * 4, stream);
    scatter_co<<<cgrid, 256, 0, stream>>>(A0, co_s, co_d, P1, degC, Eco);
    transform_kernel<4, false, true><<<blkA, 256, 0, stream>>>(P1, nullptr, A0, BPc0, degC, b_co, nullptr, A0, NA);

    // ---- Layer 2 ----
    hipMemsetAsync(P1, 0, (size_t)NP * DD * 4, stream);
    hipMemsetAsync(A1b, 0, (size_t)NA * DD * 4, stream);
    hipMemsetAsync(degP, 0, (size_t)NP * 4, stream);
    hipMemsetAsync(degA, 0, (size_t)NA * 4, stream);
    scatter_main<<<sgrid, 256, 0, stream>>>(A0, P0, a_idx, p_idx, P1, A1b, degP, degA, E);
    transform_kernel<8, true, false><<<blkP, 256, 0, stream>>>(P1, P0, nullptr, BPp1, degP, b_a2p + 128, b_pself + 128, P1, NP);
    transform_kernel<8, true, false><<<blkA, 256, 0, stream>>>(A1b, A0, nullptr, BPa1, degA, b_p2a + 128, b_aself + 128, A1b, NA);
    hipMemsetAsync(P0, 0, (size_t)NA * DD * 4, stream);  // aggC l2 in P0 space
    hipMemsetAsync(degC, 0, (size_t)NA * 4, stream);
    scatter_co<<<cgrid, 256, 0, stream>>>(A1b, co_s, co_d, P0, degC, Eco);
    transform_kernel<4, false, true><<<blkA, 256, 0, stream>>>(P0, nullptr, A1b, BPc1, degC, b_co + 128, nullptr, A1b, NA);

    // ---- output ----
    dot_kernel<<<(Esup * 32 + 255) / 256, 256, 0, stream>>>(A1b, P1, s0, s1, (float*)d_out, Esup);
}

// Round 2
// 833.582 us; speedup vs baseline: 5.7264x; 5.7264x over previous
//
#include <hip/hip_runtime.h>

#define DD 128

typedef __attribute__((ext_vector_type(8))) short short8;
typedef __attribute__((ext_vector_type(4))) float f32x4;

__device__ inline short f2bf(float f) {
    unsigned u = __float_as_uint(f);
    unsigned r = (u + 0x7fffu + ((u >> 16) & 1u)) >> 16;
    return (short)(r & 0xffffu);
}

// ---------------- weight pack: fragment-order bf16 B for mfma_f32_16x16x32_bf16 ----------------
// Bpack[((t*ktiles + kk)*64 + lane)*8 + j] = Wcat[n][k], n = t*16 + (lane&15), k = kk*32 + (lane>>4)*8 + j
__global__ void pack_w(const float* __restrict__ W1, const float* __restrict__ W2,
                       short* __restrict__ dst, int ktiles) {
    int idx = blockIdx.x * blockDim.x + threadIdx.x;
    int total = 8 * ktiles * 64;
    if (idx >= total) return;
    int lane = idx & 63;
    int kk = (idx >> 6) % ktiles;
    int t = (idx >> 6) / ktiles;
    int n = t * 16 + (lane & 15);
    int kbase = kk * 32 + (lane >> 4) * 8;
    short8 v;
#pragma unroll
    for (int j = 0; j < 8; ++j) {
        int k = kbase + j;
        float f = (k < 128) ? W1[n * 128 + k] : W2[n * 128 + (k - 128)];
        v[j] = f2bf(f);
    }
    *(short8*)(dst + (size_t)idx * 8) = v;
}

// ---------------- CSR build ----------------
__global__ __launch_bounds__(256) void count_main(const int* __restrict__ aidx,
                                                  const int* __restrict__ pidx,
                                                  int* __restrict__ cntP, int* __restrict__ cntA, int E) {
    int e = blockIdx.x * blockDim.x + threadIdx.x;
    if (e >= E) return;
    atomicAdd(&cntP[pidx[e]], 1);
    atomicAdd(&cntA[aidx[e]], 1);
}

__global__ __launch_bounds__(256) void count_co(const int* __restrict__ dst, int* __restrict__ cntC, int E) {
    int e = blockIdx.x * blockDim.x + threadIdx.x;
    if (e >= E) return;
    atomicAdd(&cntC[dst[e]], 1);
}

// block-level scan: 1024 items/block (256 thr x 4)
__global__ __launch_bounds__(256) void scan_local(const int* __restrict__ cnt, int* __restrict__ row,
                                                  int* __restrict__ partials, int N) {
    __shared__ int sh[256];
    int t = threadIdx.x;
    int base = blockIdx.x * 1024 + t * 4;
    int v0 = 0, v1 = 0, v2 = 0, v3 = 0;
    if (base + 0 < N) v0 = cnt[base + 0];
    if (base + 1 < N) v1 = cnt[base + 1];
    if (base + 2 < N) v2 = cnt[base + 2];
    if (base + 3 < N) v3 = cnt[base + 3];
    sh[t] = v0 + v1 + v2 + v3;
    __syncthreads();
    for (int off = 1; off < 256; off <<= 1) {
        int y = (t >= off) ? sh[t - off] : 0;
        __syncthreads();
        sh[t] += y;
        __syncthreads();
    }
    int excl = (t > 0) ? sh[t - 1] : 0;
    if (t == 255) partials[blockIdx.x] = sh[255];
    if (base + 0 < N) row[base + 0] = excl; excl += v0;
    if (base + 1 < N) row[base + 1] = excl; excl += v1;
    if (base + 2 < N) row[base + 2] = excl; excl += v2;
    if (base + 3 < N) row[base + 3] = excl;
}

__global__ __launch_bounds__(256) void scan_partials(int* __restrict__ partials, int nb) {
    __shared__ int sh[256];
    int t = threadIdx.x;
    int v = (t < nb) ? partials[t] : 0;
    sh[t] = v;
    __syncthreads();
    for (int off = 1; off < 256; off <<= 1) {
        int y = (t >= off) ? sh[t - off] : 0;
        __syncthreads();
        sh[t] += y;
        __syncthreads();
    }
    if (t < nb) partials[t] = (t > 0) ? sh[t - 1] : 0;
}

__global__ __launch_bounds__(256) void scan_finalize(int* __restrict__ row, int* __restrict__ cur,
                                                     const int* __restrict__ partials, int N) {
    int i = blockIdx.x * blockDim.x + threadIdx.x;
    if (i >= N) return;
    int r = row[i] + partials[i >> 10];
    row[i] = r;
    cur[i] = r;
}

__global__ __launch_bounds__(256) void fill_main(const int* __restrict__ aidx, const int* __restrict__ pidx,
                                                 int* __restrict__ curP, int* __restrict__ curA,
                                                 int* __restrict__ adjP, int* __restrict__ adjA, int E) {
    int e = blockIdx.x * blockDim.x + threadIdx.x;
    if (e >= E) return;
    int a = aidx[e], p = pidx[e];
    adjP[atomicAdd(&curP[p], 1)] = a;
    adjA[atomicAdd(&curA[a], 1)] = p;
}

__global__ __launch_bounds__(256) void fill_co(const int* __restrict__ src, const int* __restrict__ dst,
                                               int* __restrict__ curC, int* __restrict__ adjC, int E) {
    int e = blockIdx.x * blockDim.x + threadIdx.x;
    if (e >= E) return;
    adjC[atomicAdd(&curC[dst[e]], 1)] = src[e];
}

// ---------------- gather: out[node] = sum_{s in adj[node]} src[s] ----------------
__global__ __launch_bounds__(256) void gather_kernel(
    const float* __restrict__ src, const int* __restrict__ adj,
    const int* __restrict__ row, const int* __restrict__ cnt,
    float* __restrict__ out, int N) {
    int g = blockIdx.x * blockDim.x + threadIdx.x;
    int node = g >> 5;
    int l = g & 31;
    if (node >= N) return;
    int start = row[node], d = cnt[node];
    float4 acc = {0.f, 0.f, 0.f, 0.f};
    for (int i = 0; i < d; ++i) {
        int s = adj[start + i];
        float4 v = *(const float4*)(src + (size_t)s * DD + l * 4);
        acc.x += v.x; acc.y += v.y; acc.z += v.z; acc.w += v.w;
    }
    *(float4*)(out + (size_t)node * DD + l * 4) = acc;
}

// ---------------- fused node transform: out = A1@W1.T (+ A2@W2.T) + cnt*b1 (+ b2) (+ base) ----------------
template <int KTILES, bool HAS_B2, bool ADD_BASE>
__global__ __launch_bounds__(256) void transform_kernel(
    const float* __restrict__ A1, const float* __restrict__ A2,
    const float* __restrict__ base, const short* __restrict__ Bpack,
    const int* __restrict__ cnt, const float* __restrict__ b1,
    const float* __restrict__ b2, float* __restrict__ out, int M) {
    const int wave = threadIdx.x >> 6;
    const int lane = threadIdx.x & 63;
    const int kg = lane >> 4;
    const int rowBase = blockIdx.x * 64 + wave * 16;
    const int arow = rowBase + (lane & 15);
    const int arow_c = arow < M ? arow : (M - 1);

    f32x4 acc[8];
#pragma unroll
    for (int t = 0; t < 8; ++t) acc[t] = (f32x4){0.f, 0.f, 0.f, 0.f};

#pragma unroll
    for (int kk = 0; kk < KTILES; ++kk) {
        int k = kk * 32 + kg * 8;
        const float* src;
        if (KTILES == 8 && kk >= 4) src = A2 + (size_t)arow_c * DD + (k - 128);
        else                        src = A1 + (size_t)arow_c * DD + k;
        float4 u0 = *(const float4*)(src);
        float4 u1 = *(const float4*)(src + 4);
        short8 af;
        af[0] = f2bf(u0.x); af[1] = f2bf(u0.y); af[2] = f2bf(u0.z); af[3] = f2bf(u0.w);
        af[4] = f2bf(u1.x); af[5] = f2bf(u1.y); af[6] = f2bf(u1.z); af[7] = f2bf(u1.w);
#pragma unroll
        for (int t = 0; t < 8; ++t) {
            short8 bf = *(const short8*)(Bpack + ((size_t)(t * KTILES + kk) * 64 + lane) * 8);
            acc[t] = __builtin_amdgcn_mfma_f32_16x16x32_bf16(af, bf, acc[t], 0, 0, 0);
        }
    }

    const int col0 = lane & 15;
    const int crow0 = rowBase + kg * 4;
#pragma unroll
    for (int t = 0; t < 8; ++t) {
        int col = t * 16 + col0;
        float bb = b1[col];
        float b2v = HAS_B2 ? b2[col] : 0.f;
#pragma unroll
        for (int r = 0; r < 4; ++r) {
            int row = crow0 + r;
            if (row < M) {
                float v = acc[t][r] + (float)cnt[row] * bb + b2v;
                if (ADD_BASE) v += base[(size_t)row * DD + col];
                out[(size_t)row * DD + col] = v;
            }
        }
    }
}

// ---------------- supervision dot ----------------
__global__ __launch_bounds__(256) void dot_kernel(
    const float* __restrict__ xa, const float* __restrict__ xp,
    const int* __restrict__ s0, const int* __restrict__ s1,
    float* __restrict__ out, int E) {
    int g = blockIdx.x * blockDim.x + threadIdx.x;
    int e = g >> 5;
    int l = g & 31;
    if (e >= E) return;
    int a = s0[e], p = s1[e];
    float4 va = *(const float4*)(xa + (size_t)a * DD + l * 4);
    float4 vp = *(const float4*)(xp + (size_t)p * DD + l * 4);
    float s = va.x * vp.x + va.y * vp.y + va.z * vp.z + va.w * vp.w;
    s += __shfl_xor(s, 1); s += __shfl_xor(s, 2); s += __shfl_xor(s, 4);
    s += __shfl_xor(s, 8); s += __shfl_xor(s, 16);
    if (l == 0) out[e] = s;
}

extern "C" void kernel_launch(void* const* d_in, const int* in_sizes, int n_in,
                              void* d_out, int out_size, void* d_ws, size_t ws_size,
                              hipStream_t stream) {
    const float* xa_in = (const float*)d_in[0];
    const float* xp_in = (const float*)d_in[1];
    const int* eidx = (const int*)d_in[2];
    const int* co = (const int*)d_in[3];
    const int* sup = (const int*)d_in[4];
    const float* W_a2p = (const float*)d_in[5];
    const float* b_a2p = (const float*)d_in[6];
    const float* W_p2a = (const float*)d_in[7];
    const float* b_p2a = (const float*)d_in[8];
    const float* W_aself = (const float*)d_in[9];
    const float* b_aself = (const float*)d_in[10];
    const float* W_pself = (const float*)d_in[11];
    const float* b_pself = (const float*)d_in[12];
    const float* W_co = (const float*)d_in[13];
    const float* b_co = (const float*)d_in[14];

    const int NA = in_sizes[0] / DD;
    const int NP = in_sizes[1] / DD;
    const int E = in_sizes[2] / 2;
    const int Eco = in_sizes[3] / 2;
    const int Esup = in_sizes[4] / 2;
    const int* a_idx = eidx;
    const int* p_idx = eidx + E;
    const int* co_s = co;
    const int* co_d = co + Eco;
    const int* s0 = sup;
    const int* s1 = sup + Esup;

    char* w = (char*)d_ws;
    auto carve = [&](size_t bytes) -> char* {
        char* p = w;
        w += (bytes + 255) & ~(size_t)255;
        return p;
    };
    float* P0 = (float*)carve((size_t)NP * DD * 4);   // paper agg/out l1 ; co agg buffer reuse
    float* P1 = (float*)carve((size_t)NP * DD * 4);   // co agg l1 / paper agg+out l2
    float* A0 = (float*)carve((size_t)NA * DD * 4);   // author agg/out l1 / co agg l2
    float* A1b = (float*)carve((size_t)NA * DD * 4);  // author agg/out l2
    int* cntP = (int*)carve((size_t)NP * 4);
    int* rowP = (int*)carve((size_t)NP * 4);
    int* curP = (int*)carve((size_t)NP * 4);
    int* cntA = (int*)carve((size_t)NA * 4);
    int* rowA = (int*)carve((size_t)NA * 4);
    int* curA = (int*)carve((size_t)NA * 4);
    int* cntC = (int*)carve((size_t)NA * 4);
    int* rowC = (int*)carve((size_t)NA * 4);
    int* curC = (int*)carve((size_t)NA * 4);
    int* adjP = (int*)carve((size_t)E * 4);
    int* adjA = (int*)carve((size_t)E * 4);
    int* adjC = (int*)carve((size_t)Eco * 4);
    int* partP = (int*)carve(256 * 4);
    int* partA = (int*)carve(256 * 4);
    int* partC = (int*)carve(256 * 4);
    short* BPp0 = (short*)carve(8 * 8 * 64 * 8 * 2);
    short* BPp1 = (short*)carve(8 * 8 * 64 * 8 * 2);
    short* BPa0 = (short*)carve(8 * 8 * 64 * 8 * 2);
    short* BPa1 = (short*)carve(8 * 8 * 64 * 8 * 2);
    short* BPc0 = (short*)carve(8 * 4 * 64 * 8 * 2);
    short* BPc1 = (short*)carve(8 * 4 * 64 * 8 * 2);

    const int WL = 128 * 128;
    pack_w<<<16, 256, 0, stream>>>(W_a2p, W_pself, BPp0, 8);
    pack_w<<<16, 256, 0, stream>>>(W_a2p + WL, W_pself + WL, BPp1, 8);
    pack_w<<<16, 256, 0, stream>>>(W_p2a, W_aself, BPa0, 8);
    pack_w<<<16, 256, 0, stream>>>(W_p2a + WL, W_aself + WL, BPa1, 8);
    pack_w<<<8, 256, 0, stream>>>(W_co, nullptr, BPc0, 4);
    pack_w<<<8, 256, 0, stream>>>(W_co + WL, nullptr, BPc1, 4);

    // ---- CSR build (once; reused for both layers) ----
    hipMemsetAsync(cntP, 0, (size_t)NP * 4, stream);
    hipMemsetAsync(cntA, 0, (size_t)NA * 4, stream);
    hipMemsetAsync(cntC, 0, (size_t)NA * 4, stream);
    count_main<<<(E + 255) / 256, 256, 0, stream>>>(a_idx, p_idx, cntP, cntA, E);
    count_co<<<(Eco + 255) / 256, 256, 0, stream>>>(co_d, cntC, Eco);
    const int nbP = (NP + 1023) / 1024;
    const int nbA = (NA + 1023) / 1024;
    scan_local<<<nbP, 256, 0, stream>>>(cntP, rowP, partP, NP);
    scan_partials<<<1, 256, 0, stream>>>(partP, nbP);
    scan_finalize<<<(NP + 255) / 256, 256, 0, stream>>>(rowP, curP, partP, NP);
    scan_local<<<nbA, 256, 0, stream>>>(cntA, rowA, partA, NA);
    scan_partials<<<1, 256, 0, stream>>>(partA, nbA);
    scan_finalize<<<(NA + 255) / 256, 256, 0, stream>>>(rowA, curA, partA, NA);
    scan_local<<<nbA, 256, 0, stream>>>(cntC, rowC, partC, NA);
    scan_partials<<<1, 256, 0, stream>>>(partC, nbA);
    scan_finalize<<<(NA + 255) / 256, 256, 0, stream>>>(rowC, curC, partC, NA);
    fill_main<<<(E + 255) / 256, 256, 0, stream>>>(a_idx, p_idx, curP, curA, adjP, adjA, E);
    fill_co<<<(Eco + 255) / 256, 256, 0, stream>>>(co_s, co_d, curC, adjC, Eco);

    const int blkP = (NP + 63) / 64;
    const int blkA = (NA + 63) / 64;
    const int gP = (NP * 32 + 255) / 256;
    const int gA = (NA * 32 + 255) / 256;

    // ---- Layer 1 ----
    gather_kernel<<<gP, 256, 0, stream>>>(xa_in, adjP, rowP, cntP, P0, NP);
    transform_kernel<8, true, false><<<blkP, 256, 0, stream>>>(P0, xp_in, nullptr, BPp0, cntP, b_a2p, b_pself, P0, NP);
    gather_kernel<<<gA, 256, 0, stream>>>(xp_in, adjA, rowA, cntA, A0, NA);
    transform_kernel<8, true, false><<<blkA, 256, 0, stream>>>(A0, xa_in, nullptr, BPa0, cntA, b_p2a, b_aself, A0, NA);
    gather_kernel<<<gA, 256, 0, stream>>>(A0, adjC, rowC, cntC, P1, NA);
    transform_kernel<4, false, true><<<blkA, 256, 0, stream>>>(P1, nullptr, A0, BPc0, cntC, b_co, nullptr, A0, NA);

    // ---- Layer 2 ----
    gather_kernel<<<gP, 256, 0, stream>>>(A0, adjP, rowP, cntP, P1, NP);
    transform_kernel<8, true, false><<<blkP, 256, 0, stream>>>(P1, P0, nullptr, BPp1, cntP, b_a2p + 128, b_pself + 128, P1, NP);
    gather_kernel<<<gA, 256, 0, stream>>>(P0, adjA, rowA, cntA, A1b, NA);
    transform_kernel<8, true, false><<<blkA, 256, 0, stream>>>(A1b, A0, nullptr, BPa1, cntA, b_p2a + 128, b_aself + 128, A1b, NA);
    gather_kernel<<<gA, 256, 0, stream>>>(A1b, adjC, rowC, cntC, A0, NA);
    transform_kernel<4, false, true><<<blkA, 256, 0, stream>>>(A0, nullptr, A1b, BPc1, cntC, b_co + 128, nullptr, A1b, NA);

    // ---- output ----
    dot_kernel<<<(Esup * 32 + 255) / 256, 256, 0, stream>>>(A1b, P1, s0, s1, (float*)d_out, Esup);
}